// Round 1
// baseline (576.691 us; speedup 1.0000x reference)
//
#include <hip/hip_runtime.h>
#include <hip/hip_bf16.h>
#include <cstdint>
#include <cstddef>

typedef __bf16 bf16_t;
typedef bf16_t bf16x8 __attribute__((ext_vector_type(8)));
typedef bf16_t bf16x4 __attribute__((ext_vector_type(4)));
typedef float f32x4 __attribute__((ext_vector_type(4)));

#define B_  4
#define S_  2048
#define D_  1024
#define H_  16
#define DK_ 64

// async global->LDS, 16B per lane. LDS dest must be wave-uniform base + lane*16.
__device__ __forceinline__ void gload_lds16(const bf16_t* g, bf16_t* l) {
  __builtin_amdgcn_global_load_lds(
      (__attribute__((address_space(1))) void*)(void*)g,
      (__attribute__((address_space(3))) void*)(void*)l,
      16, 0, 0);
}

__device__ __forceinline__ f32x4 mfma_bf16(bf16x8 a, bf16x8 b, f32x4 c) {
  return __builtin_amdgcn_mfma_f32_16x16x32_bf16(a, b, c, 0, 0, 0);
}

// ---------------- fp32 -> bf16 convert (vectorized) ----------------
__global__ void cvt_f32_bf16(const float* __restrict__ in, bf16_t* __restrict__ out, int n4) {
  int i = blockIdx.x * blockDim.x + threadIdx.x;
  if (i < n4) {
    float4 v = reinterpret_cast<const float4*>(in)[i];
    bf16x4 o;
    o[0] = (bf16_t)v.x; o[1] = (bf16_t)v.y; o[2] = (bf16_t)v.z; o[3] = (bf16_t)v.w;
    reinterpret_cast<bf16x4*>(out)[i] = o;
  }
}

// ---------------- GEMM 1: qkv = x @ Wqkv^T + bqkv, scatter to Q/K/V^T ----------------
// A [M=8192, K=1024] bf16 row-major; Bm [N=3072, K=1024] bf16 (K-contiguous).
// 128x128 tile, BK=32, 4 waves (2x2), each wave 64x64 = 4x4 frags of 16x16x32.
__global__ __launch_bounds__(256) void gemm_qkv(
    const bf16_t* __restrict__ A, const bf16_t* __restrict__ Bm,
    const float* __restrict__ bias,
    bf16_t* __restrict__ Qw, bf16_t* __restrict__ Kw, bf16_t* __restrict__ VT) {
  __shared__ bf16_t As[128 * 32];
  __shared__ bf16_t Bs[128 * 32];
  const int t = threadIdx.x;
  const int l = t & 63;
  const int w = t >> 6;
  const int wm = w >> 1, wn = w & 1;
  const int fr = l & 15, fh = l >> 4;     // frag row / k-half
  const int m0 = blockIdx.y * 128, n0 = blockIdx.x * 128;
  const int K = 1024;
  const int ar = t >> 2, ak = (t & 3) * 8;

  f32x4 acc[4][4] = {};

  for (int k0 = 0; k0 < K; k0 += 32) {
    gload_lds16(A + (size_t)(m0 + ar) * K + k0 + ak,        &As[t * 8]);
    gload_lds16(A + (size_t)(m0 + 64 + ar) * K + k0 + ak,   &As[2048 + t * 8]);
    gload_lds16(Bm + (size_t)(n0 + ar) * K + k0 + ak,       &Bs[t * 8]);
    gload_lds16(Bm + (size_t)(n0 + 64 + ar) * K + k0 + ak,  &Bs[2048 + t * 8]);
    __syncthreads();
    bf16x8 af[4], bfv[4];
#pragma unroll
    for (int i = 0; i < 4; ++i)
      af[i] = *reinterpret_cast<const bf16x8*>(&As[(wm * 64 + i * 16 + fr) * 32 + fh * 8]);
#pragma unroll
    for (int i = 0; i < 4; ++i)
      bfv[i] = *reinterpret_cast<const bf16x8*>(&Bs[(wn * 64 + i * 16 + fr) * 32 + fh * 8]);
#pragma unroll
    for (int mi = 0; mi < 4; ++mi)
#pragma unroll
      for (int ni = 0; ni < 4; ++ni)
        acc[mi][ni] = mfma_bf16(af[mi], bfv[ni], acc[mi][ni]);
    __syncthreads();
  }

  // epilogue: C[m][e] + bias[e] -> scatter into Q [B,H,S,DK], K [B,H,S,DK], V^T [B,H,DK,S]
#pragma unroll
  for (int mi = 0; mi < 4; ++mi) {
#pragma unroll
    for (int ni = 0; ni < 4; ++ni) {
      const int e = n0 + wn * 64 + ni * 16 + fr;
      const int sec = e >> 10;              // 0=q 1=k 2=v
      const int h = (e & 1023) >> 6, dk = e & 63;
      const float bv = bias[e];
#pragma unroll
      for (int j = 0; j < 4; ++j) {
        const int m = m0 + wm * 64 + mi * 16 + fh * 4 + j;
        const int b = m >> 11, s = m & 2047;
        const bf16_t v = (bf16_t)(acc[mi][ni][j] + bv);
        if (sec == 0)      Qw[((size_t)(b * H_ + h) * S_ + s) * DK_ + dk] = v;
        else if (sec == 1) Kw[((size_t)(b * H_ + h) * S_ + s) * DK_ + dk] = v;
        else               VT[((size_t)(b * H_ + h) * DK_ + dk) * S_ + s] = v;
      }
    }
  }
}

// ---------------- GEMM 2: out = attn_out @ Wout^T + bout (fp32 out) ----------------
__global__ __launch_bounds__(256) void gemm_out(
    const bf16_t* __restrict__ A, const bf16_t* __restrict__ Bm,
    const float* __restrict__ bias, float* __restrict__ out) {
  __shared__ bf16_t As[128 * 32];
  __shared__ bf16_t Bs[128 * 32];
  const int t = threadIdx.x;
  const int l = t & 63;
  const int w = t >> 6;
  const int wm = w >> 1, wn = w & 1;
  const int fr = l & 15, fh = l >> 4;
  const int m0 = blockIdx.y * 128, n0 = blockIdx.x * 128;
  const int K = 1024;
  const int ar = t >> 2, ak = (t & 3) * 8;

  f32x4 acc[4][4] = {};

  for (int k0 = 0; k0 < K; k0 += 32) {
    gload_lds16(A + (size_t)(m0 + ar) * K + k0 + ak,        &As[t * 8]);
    gload_lds16(A + (size_t)(m0 + 64 + ar) * K + k0 + ak,   &As[2048 + t * 8]);
    gload_lds16(Bm + (size_t)(n0 + ar) * K + k0 + ak,       &Bs[t * 8]);
    gload_lds16(Bm + (size_t)(n0 + 64 + ar) * K + k0 + ak,  &Bs[2048 + t * 8]);
    __syncthreads();
    bf16x8 af[4], bfv[4];
#pragma unroll
    for (int i = 0; i < 4; ++i)
      af[i] = *reinterpret_cast<const bf16x8*>(&As[(wm * 64 + i * 16 + fr) * 32 + fh * 8]);
#pragma unroll
    for (int i = 0; i < 4; ++i)
      bfv[i] = *reinterpret_cast<const bf16x8*>(&Bs[(wn * 64 + i * 16 + fr) * 32 + fh * 8]);
#pragma unroll
    for (int mi = 0; mi < 4; ++mi)
#pragma unroll
      for (int ni = 0; ni < 4; ++ni)
        acc[mi][ni] = mfma_bf16(af[mi], bfv[ni], acc[mi][ni]);
    __syncthreads();
  }

#pragma unroll
  for (int mi = 0; mi < 4; ++mi) {
#pragma unroll
    for (int ni = 0; ni < 4; ++ni) {
      const int e = n0 + wn * 64 + ni * 16 + fr;
      const float bv = bias[e];
#pragma unroll
      for (int j = 0; j < 4; ++j) {
        const int m = m0 + wm * 64 + mi * 16 + fh * 4 + j;
        out[(size_t)m * D_ + e] = acc[mi][ni][j] + bv;
      }
    }
  }
}

// ---------------- Flash attention ----------------
// grid: B*H * (S/64) blocks, 256 threads (4 waves). Wave w owns q-rows [q0+w*16, +16).
// KV tile = 64. Q [B,H,S,DK], K [B,H,S,DK], V^T [B,H,DK,S] all bf16.
__global__ __launch_bounds__(256) void attn_fwd(
    const bf16_t* __restrict__ Qw, const bf16_t* __restrict__ Kw,
    const bf16_t* __restrict__ VT, bf16_t* __restrict__ Aout) {
  __shared__ bf16_t P[4][16 * 64];   // per-wave private P tile (swizzled)
  const int t = threadIdx.x, l = t & 63, w = t >> 6;
  const int fr = l & 15, fh = l >> 4;
  const int bh = blockIdx.x >> 5;                  // 0..63
  const int q0 = (blockIdx.x & 31) * 64 + w * 16;  // wave's q base
  const int b = bh >> 4, h = bh & 15;

  const bf16_t* Qh = Qw + (size_t)bh * S_ * DK_;
  const bf16_t* Kh = Kw + (size_t)bh * S_ * DK_;
  const bf16_t* Vh = VT + (size_t)bh * S_ * DK_;   // [DK][S]
  bf16_t* Pw = P[w];

  // hoist Q fragments: rows fr, d = kf*32 + fh*8 .. +7
  bf16x8 qf0 = *reinterpret_cast<const bf16x8*>(&Qh[(size_t)(q0 + fr) * DK_ + fh * 8]);
  bf16x8 qf1 = *reinterpret_cast<const bf16x8*>(&Qh[(size_t)(q0 + fr) * DK_ + 32 + fh * 8]);

  float rowm[4] = {-1e30f, -1e30f, -1e30f, -1e30f};
  float rows[4] = {0.f, 0.f, 0.f, 0.f};
  f32x4 oa[4] = {};   // O accumulator: 4 dk-frags, rows fh*4+j, cols d*16+fr

  constexpr float LOG2E = 1.4426950408889634f;

  for (int kv0 = 0; kv0 < S_; kv0 += 64) {
    // --- QK^T: scores frag ni covers kv cols ni*16..+15, rows = q (C layout) ---
    f32x4 sf[4];
#pragma unroll
    for (int ni = 0; ni < 4; ++ni) {
      const bf16_t* kp = &Kh[(size_t)(kv0 + ni * 16 + fr) * DK_];
      bf16x8 kb0 = *reinterpret_cast<const bf16x8*>(kp + fh * 8);
      bf16x8 kb1 = *reinterpret_cast<const bf16x8*>(kp + 32 + fh * 8);
      f32x4 z = {};
      z = mfma_bf16(qf0, kb0, z);
      z = mfma_bf16(qf1, kb1, z);
      sf[ni] = z * 0.125f;   // 1/sqrt(64)
    }
    // --- online softmax (per lane: 4 q-rows = fh*4+j; cols spread over lanes fr) ---
#pragma unroll
    for (int j = 0; j < 4; ++j) {
      float v = fmaxf(fmaxf(sf[0][j], sf[1][j]), fmaxf(sf[2][j], sf[3][j]));
      v = fmaxf(v, __shfl_xor(v, 1));
      v = fmaxf(v, __shfl_xor(v, 2));
      v = fmaxf(v, __shfl_xor(v, 4));
      v = fmaxf(v, __shfl_xor(v, 8));
      const float mn = fmaxf(rowm[j], v);
      const float alpha = exp2f((rowm[j] - mn) * LOG2E);
      float ps = 0.f;
#pragma unroll
      for (int ni = 0; ni < 4; ++ni) {
        float p = exp2f((sf[ni][j] - mn) * LOG2E);
        sf[ni][j] = p;
        ps += p;
      }
      ps += __shfl_xor(ps, 1);
      ps += __shfl_xor(ps, 2);
      ps += __shfl_xor(ps, 4);
      ps += __shfl_xor(ps, 8);
      rows[j] = rows[j] * alpha + ps;
      rowm[j] = mn;
#pragma unroll
      for (int d = 0; d < 4; ++d) oa[d][j] *= alpha;
    }
    // --- P -> LDS (wave-private, XOR swizzle on byte bit4 by row) ---
#pragma unroll
    for (int ni = 0; ni < 4; ++ni)
#pragma unroll
      for (int j = 0; j < 4; ++j) {
        const int r = fh * 4 + j, c = ni * 16 + fr;
        const int off = (r * 128 + c * 2) ^ ((r & 7) << 4);
        *reinterpret_cast<bf16_t*>(reinterpret_cast<char*>(Pw) + off) = (bf16_t)sf[ni][j];
      }
    // --- read P as A-frags (row fr, k = kf*32 + fh*8) ---
    bf16x8 pa[2];
#pragma unroll
    for (int kf = 0; kf < 2; ++kf) {
      const int off = (fr * 128 + (kf * 32 + fh * 8) * 2) ^ ((fr & 7) << 4);
      pa[kf] = *reinterpret_cast<const bf16x8*>(reinterpret_cast<const char*>(Pw) + off);
    }
    // --- PV: O[q][dk] += P @ V ; B operand from V^T (contiguous along s) ---
#pragma unroll
    for (int d = 0; d < 4; ++d) {
      const bf16_t* vp = &Vh[(size_t)(d * 16 + fr) * S_ + kv0];
      bf16x8 vb0 = *reinterpret_cast<const bf16x8*>(vp + fh * 8);
      bf16x8 vb1 = *reinterpret_cast<const bf16x8*>(vp + 32 + fh * 8);
      oa[d] = mfma_bf16(pa[0], vb0, oa[d]);
      oa[d] = mfma_bf16(pa[1], vb1, oa[d]);
    }
  }

  // epilogue: normalize and write [B,S,D] bf16
#pragma unroll
  for (int j = 0; j < 4; ++j) {
    const float inv = 1.0f / rows[j];
    const int s = q0 + fh * 4 + j;
#pragma unroll
    for (int d = 0; d < 4; ++d) {
      const int col = h * 64 + d * 16 + fr;
      Aout[((size_t)(b * S_ + s)) * D_ + col] = (bf16_t)(oa[d][j] * inv);
    }
  }
}

// ---------------- launch ----------------
extern "C" void kernel_launch(void* const* d_in, const int* in_sizes, int n_in,
                              void* d_out, int out_size, void* d_ws, size_t ws_size,
                              hipStream_t stream) {
  const float* x    = (const float*)d_in[0];
  const float* Wqkv = (const float*)d_in[1];
  const float* bqkv = (const float*)d_in[2];
  const float* Wout = (const float*)d_in[3];
  const float* bout = (const float*)d_in[4];
  float* out = (float*)d_out;

  char* ws = (char*)d_ws;
  bf16_t* xb    = (bf16_t*)(ws);                 // 8388608 el = 16 MB
  bf16_t* wqkvb = (bf16_t*)(ws + 16777216);      // 3145728 el = 6 MB
  bf16_t* woutb = (bf16_t*)(ws + 23068672);      // 1048576 el = 2 MB
  bf16_t* Qw    = (bf16_t*)(ws + 25165824);      // 8388608 el
  bf16_t* Kw    = (bf16_t*)(ws + 41943040);      // 8388608 el
  bf16_t* VT    = (bf16_t*)(ws + 58720256);      // 8388608 el (transposed V)
  bf16_t* aout  = (bf16_t*)(ws + 75497472);      // 8388608 el

  cvt_f32_bf16<<<8192, 256, 0, stream>>>(x, xb, 2097152);
  cvt_f32_bf16<<<3072, 256, 0, stream>>>(Wqkv, wqkvb, 786432);
  cvt_f32_bf16<<<1024, 256, 0, stream>>>(Wout, woutb, 262144);

  gemm_qkv<<<dim3(24, 64), 256, 0, stream>>>(xb, wqkvb, bqkv, Qw, Kw, VT);
  attn_fwd<<<2048, 256, 0, stream>>>(Qw, Kw, VT, aout);
  gemm_out<<<dim3(8, 64), 256, 0, stream>>>(aout, woutb, bout, out);
}

// Round 2
// 360.837 us; speedup vs baseline: 1.5982x; 1.5982x over previous
//
#include <hip/hip_runtime.h>
#include <hip/hip_bf16.h>
#include <cstdint>
#include <cstddef>

typedef __bf16 bf16_t;
typedef bf16_t bf16x8 __attribute__((ext_vector_type(8)));
typedef bf16_t bf16x4 __attribute__((ext_vector_type(4)));
typedef bf16_t bf16x2 __attribute__((ext_vector_type(2)));
typedef float f32x4 __attribute__((ext_vector_type(4)));
typedef float f32x16 __attribute__((ext_vector_type(16)));
typedef unsigned int u32x4 __attribute__((ext_vector_type(4)));

#define B_  4
#define S_  2048
#define D_  1024
#define H_  16
#define DK_ 64

// log2(e)/8 : folds the 1/sqrt(64) softmax scale AND ln->log2 conversion into Q.
#define QSCALE 0.18033688011112042f

// async global->LDS, 16B per lane. LDS dest must be wave-uniform base + lane*16.
__device__ __forceinline__ void gload_lds16(const bf16_t* g, bf16_t* l) {
  __builtin_amdgcn_global_load_lds(
      (__attribute__((address_space(1))) void*)(void*)g,
      (__attribute__((address_space(3))) void*)(void*)l,
      16, 0, 0);
}

__device__ __forceinline__ f32x4 mfma_bf16(bf16x8 a, bf16x8 b, f32x4 c) {
  return __builtin_amdgcn_mfma_f32_16x16x32_bf16(a, b, c, 0, 0, 0);
}
__device__ __forceinline__ f32x16 mfma32(bf16x8 a, bf16x8 b, f32x16 c) {
  return __builtin_amdgcn_mfma_f32_32x32x16_bf16(a, b, c, 0, 0, 0);
}

__device__ __forceinline__ unsigned pk2(float a, float b) {
  bf16x2 v; v[0] = (bf16_t)a; v[1] = (bf16_t)b;
  return __builtin_bit_cast(unsigned, v);
}

// ---------------- fp32 -> bf16 convert (vectorized) ----------------
__global__ void cvt_f32_bf16(const float* __restrict__ in, bf16_t* __restrict__ out, int n4) {
  int i = blockIdx.x * blockDim.x + threadIdx.x;
  if (i < n4) {
    float4 v = reinterpret_cast<const float4*>(in)[i];
    bf16x4 o;
    o[0] = (bf16_t)v.x; o[1] = (bf16_t)v.y; o[2] = (bf16_t)v.z; o[3] = (bf16_t)v.w;
    reinterpret_cast<bf16x4*>(out)[i] = o;
  }
}

// ---------------- GEMM 1: qkv = x @ Wqkv^T + bqkv, scatter to Q/K/V^T ----------------
__global__ __launch_bounds__(256) void gemm_qkv(
    const bf16_t* __restrict__ A, const bf16_t* __restrict__ Bm,
    const float* __restrict__ bias,
    bf16_t* __restrict__ Qw, bf16_t* __restrict__ Kw, bf16_t* __restrict__ VT) {
  __shared__ bf16_t As[128 * 32];
  __shared__ bf16_t Bs[128 * 32];
  const int t = threadIdx.x;
  const int l = t & 63;
  const int w = t >> 6;
  const int wm = w >> 1, wn = w & 1;
  const int fr = l & 15, fh = l >> 4;     // frag row / k-half
  const int m0 = blockIdx.y * 128, n0 = blockIdx.x * 128;
  const int K = 1024;
  const int ar = t >> 2, ak = (t & 3) * 8;

  f32x4 acc[4][4] = {};

  for (int k0 = 0; k0 < K; k0 += 32) {
    gload_lds16(A + (size_t)(m0 + ar) * K + k0 + ak,        &As[t * 8]);
    gload_lds16(A + (size_t)(m0 + 64 + ar) * K + k0 + ak,   &As[2048 + t * 8]);
    gload_lds16(Bm + (size_t)(n0 + ar) * K + k0 + ak,       &Bs[t * 8]);
    gload_lds16(Bm + (size_t)(n0 + 64 + ar) * K + k0 + ak,  &Bs[2048 + t * 8]);
    __syncthreads();
    bf16x8 af[4], bfv[4];
#pragma unroll
    for (int i = 0; i < 4; ++i)
      af[i] = *reinterpret_cast<const bf16x8*>(&As[(wm * 64 + i * 16 + fr) * 32 + fh * 8]);
#pragma unroll
    for (int i = 0; i < 4; ++i)
      bfv[i] = *reinterpret_cast<const bf16x8*>(&Bs[(wn * 64 + i * 16 + fr) * 32 + fh * 8]);
#pragma unroll
    for (int mi = 0; mi < 4; ++mi)
#pragma unroll
      for (int ni = 0; ni < 4; ++ni)
        acc[mi][ni] = mfma_bf16(af[mi], bfv[ni], acc[mi][ni]);
    __syncthreads();
  }

  // epilogue: C[m][e] + bias[e] -> scatter into Q (pre-scaled), K, V^T
#pragma unroll
  for (int mi = 0; mi < 4; ++mi) {
#pragma unroll
    for (int ni = 0; ni < 4; ++ni) {
      const int e = n0 + wn * 64 + ni * 16 + fr;
      const int sec = e >> 10;              // 0=q 1=k 2=v
      const int h = (e & 1023) >> 6, dk = e & 63;
      const float bv = bias[e];
#pragma unroll
      for (int j = 0; j < 4; ++j) {
        const int m = m0 + wm * 64 + mi * 16 + fh * 4 + j;
        const int b = m >> 11, s = m & 2047;
        const float val = acc[mi][ni][j] + bv;
        if (sec == 0)      Qw[((size_t)(b * H_ + h) * S_ + s) * DK_ + dk] = (bf16_t)(val * QSCALE);
        else if (sec == 1) Kw[((size_t)(b * H_ + h) * S_ + s) * DK_ + dk] = (bf16_t)val;
        else               VT[((size_t)(b * H_ + h) * DK_ + dk) * S_ + s] = (bf16_t)val;
      }
    }
  }
}

// ---------------- GEMM 2: out = attn_out @ Wout^T + bout (fp32 out) ----------------
__global__ __launch_bounds__(256) void gemm_out(
    const bf16_t* __restrict__ A, const bf16_t* __restrict__ Bm,
    const float* __restrict__ bias, float* __restrict__ out) {
  __shared__ bf16_t As[128 * 32];
  __shared__ bf16_t Bs[128 * 32];
  const int t = threadIdx.x;
  const int l = t & 63;
  const int w = t >> 6;
  const int wm = w >> 1, wn = w & 1;
  const int fr = l & 15, fh = l >> 4;
  const int m0 = blockIdx.y * 128, n0 = blockIdx.x * 128;
  const int K = 1024;
  const int ar = t >> 2, ak = (t & 3) * 8;

  f32x4 acc[4][4] = {};

  for (int k0 = 0; k0 < K; k0 += 32) {
    gload_lds16(A + (size_t)(m0 + ar) * K + k0 + ak,        &As[t * 8]);
    gload_lds16(A + (size_t)(m0 + 64 + ar) * K + k0 + ak,   &As[2048 + t * 8]);
    gload_lds16(Bm + (size_t)(n0 + ar) * K + k0 + ak,       &Bs[t * 8]);
    gload_lds16(Bm + (size_t)(n0 + 64 + ar) * K + k0 + ak,  &Bs[2048 + t * 8]);
    __syncthreads();
    bf16x8 af[4], bfv[4];
#pragma unroll
    for (int i = 0; i < 4; ++i)
      af[i] = *reinterpret_cast<const bf16x8*>(&As[(wm * 64 + i * 16 + fr) * 32 + fh * 8]);
#pragma unroll
    for (int i = 0; i < 4; ++i)
      bfv[i] = *reinterpret_cast<const bf16x8*>(&Bs[(wn * 64 + i * 16 + fr) * 32 + fh * 8]);
#pragma unroll
    for (int mi = 0; mi < 4; ++mi)
#pragma unroll
      for (int ni = 0; ni < 4; ++ni)
        acc[mi][ni] = mfma_bf16(af[mi], bfv[ni], acc[mi][ni]);
    __syncthreads();
  }

#pragma unroll
  for (int mi = 0; mi < 4; ++mi) {
#pragma unroll
    for (int ni = 0; ni < 4; ++ni) {
      const int e = n0 + wn * 64 + ni * 16 + fr;
      const float bv = bias[e];
#pragma unroll
      for (int j = 0; j < 4; ++j) {
        const int m = m0 + wm * 64 + mi * 16 + fh * 4 + j;
        out[(size_t)m * D_ + e] = acc[mi][ni][j] + bv;
      }
    }
  }
}

// ---------------- Flash attention, swapped-operand 32x32 structure ----------------
// grid: 1024 blocks x 256 threads (4 waves). Each wave owns 32 q-rows.
// Swapped QK^T: S^T = K·Q^T via mfma32(A=K-frag, B=Q-frag) -> lane owns q = lane&31,
// kv rows live in-register (rowpat(reg,hi) = (reg&3)+8*(reg>>2)+4*hi).
// No LDS. Online softmax with wave-uniform deferred max (T13, thr=8 in log2 domain;
// Q pre-scaled by log2(e)/8 so scores are already log2-domain).
__global__ __launch_bounds__(256) void attn_fwd(
    const bf16_t* __restrict__ Qw, const bf16_t* __restrict__ Kw,
    const bf16_t* __restrict__ VT, bf16_t* __restrict__ Aout) {
  const int t = threadIdx.x, l = t & 63, w = t >> 6;
  const int lq = l & 31;          // this lane's q-column
  const int hi = l >> 5;

  // bijective XCD swizzle: 1024 blocks, 8 XCDs -> each XCD gets 8 contiguous heads
  const int bid = (int)blockIdx.x;
  const int swz = (bid & 7) * 128 + (bid >> 3);
  const int bh = swz >> 4;                 // 0..63
  const int q0 = (swz & 15) * 128 + w * 32;
  const int b = bh >> 4, h = bh & 15;

  const bf16_t* Qh = Qw + (size_t)bh * S_ * DK_;
  const bf16_t* Kh = Kw + (size_t)bh * S_ * DK_;
  const bf16_t* Vh = VT + (size_t)bh * S_ * DK_;   // [DK][S]

  // Q B-operand frags: lane holds Q[q0+lq][d*16 + hi*8 .. +8], d = 0..3
  bf16x8 qf[4];
#pragma unroll
  for (int d = 0; d < 4; ++d)
    qf[d] = *reinterpret_cast<const bf16x8*>(&Qh[(size_t)(q0 + lq) * DK_ + d * 16 + hi * 8]);

  f32x16 oa0 = {}, oa1 = {};     // O accum: rows q=rowpat, cols dk = lq (+32)
  float m = -1e30f, rs = 0.f;

  for (int kv0 = 0; kv0 < S_; kv0 += 64) {
    // --- QK^T (swapped): cs[s] = S^T[kv0+32s+rowpat][q0+lq], log2 domain ---
    f32x16 cs[2]; cs[0] = {}; cs[1] = {};
#pragma unroll
    for (int d = 0; d < 4; ++d) {
      bf16x8 k0 = *reinterpret_cast<const bf16x8*>(&Kh[(size_t)(kv0 + lq) * DK_ + d * 16 + hi * 8]);
      bf16x8 k1 = *reinterpret_cast<const bf16x8*>(&Kh[(size_t)(kv0 + 32 + lq) * DK_ + d * 16 + hi * 8]);
      cs[0] = mfma32(k0, qf[d], cs[0]);
      cs[1] = mfma32(k1, qf[d], cs[1]);
    }

    // --- tile max (per-lane tree), deferred wave-uniform max update ---
    float tm = cs[0][0];
#pragma unroll
    for (int r = 1; r < 16; ++r) tm = fmaxf(tm, cs[0][r]);
#pragma unroll
    for (int r = 0; r < 16; ++r) tm = fmaxf(tm, cs[1][r]);
    if (__any(tm > m + 8.f)) {
#pragma unroll
      for (int sh = 1; sh < 64; sh <<= 1) tm = fmaxf(tm, __shfl_xor(tm, sh));
      const float alpha = __builtin_amdgcn_exp2f(m - tm);
      m = tm;
      rs *= alpha;
#pragma unroll
      for (int r = 0; r < 16; ++r) { oa0[r] *= alpha; oa1[r] *= alpha; }
    }

    // --- per 32-kv subtile: exp, sum, pack, lane-pair exchange, PV ---
#pragma unroll
    for (int s = 0; s < 2; ++s) {
      // V B-operand frags for this subtile: V[kv][dk] from V^T rows (contiguous kv)
      const size_t vbase = (size_t)kv0 + s * 32 + hi * 8;
      bf16x8 v00 = *reinterpret_cast<const bf16x8*>(&Vh[(size_t)lq        * S_ + vbase]);
      bf16x8 v01 = *reinterpret_cast<const bf16x8*>(&Vh[(size_t)(32 + lq) * S_ + vbase]);
      bf16x8 v10 = *reinterpret_cast<const bf16x8*>(&Vh[(size_t)lq        * S_ + vbase + 16]);
      bf16x8 v11 = *reinterpret_cast<const bf16x8*>(&Vh[(size_t)(32 + lq) * S_ + vbase + 16]);

      float pvv[16];
      float ps0 = 0.f, ps1 = 0.f, ps2 = 0.f, ps3 = 0.f;
#pragma unroll
      for (int r = 0; r < 16; r += 4) {
        pvv[r]     = __builtin_amdgcn_exp2f(cs[s][r]     - m);
        pvv[r + 1] = __builtin_amdgcn_exp2f(cs[s][r + 1] - m);
        pvv[r + 2] = __builtin_amdgcn_exp2f(cs[s][r + 2] - m);
        pvv[r + 3] = __builtin_amdgcn_exp2f(cs[s][r + 3] - m);
        ps0 += pvv[r]; ps1 += pvv[r + 1]; ps2 += pvv[r + 2]; ps3 += pvv[r + 3];
      }
      rs += (ps0 + ps1) + (ps2 + ps3);

      // packs: Ab[b] = kv {8b+4hi+0,1}, Bb[b] = kv {8b+4hi+2,3}
      unsigned Ab[4], Bb[4];
#pragma unroll
      for (int bb = 0; bb < 4; ++bb) {
        Ab[bb] = pk2(pvv[4 * bb],     pvv[4 * bb + 1]);
        Bb[bb] = pk2(pvv[4 * bb + 2], pvv[4 * bb + 3]);
      }
      // exchange between lane l <-> l+32 (same q) to build contiguous A-frags
#pragma unroll
      for (int tt = 0; tt < 2; ++tt) {
        const unsigned sA0 = (unsigned)__shfl_xor((int)Ab[2 * tt], 32);
        const unsigned sA1 = (unsigned)__shfl_xor((int)Ab[2 * tt + 1], 32);
        const unsigned sB0 = (unsigned)__shfl_xor((int)Bb[2 * tt], 32);
        const unsigned sB1 = (unsigned)__shfl_xor((int)Bb[2 * tt + 1], 32);
        u32x4 fw;
        fw[0] = hi ? sA1 : Ab[2 * tt];
        fw[1] = hi ? sB1 : Bb[2 * tt];
        fw[2] = hi ? Ab[2 * tt + 1] : sA0;
        fw[3] = hi ? Bb[2 * tt + 1] : sB0;
        const bf16x8 pa = __builtin_bit_cast(bf16x8, fw);
        oa0 = mfma32(pa, (tt ? v10 : v00), oa0);
        oa1 = mfma32(pa, (tt ? v11 : v01), oa1);
      }
    }
  }

  // --- epilogue: combine lane pair sums, redistribute 1/rs, write bf16 ---
  rs += __shfl_xor(rs, 32);
  const float inv = 1.0f / rs;     // valid for q = lq (both hi copies identical)
#pragma unroll
  for (int r = 0; r < 16; ++r) {
    const int ql = (r & 3) + 8 * (r >> 2) + 4 * hi;
    const float ir = __shfl(inv, ql);
    const size_t row = (size_t)(b * S_ + q0 + ql) * D_ + h * 64 + lq;
    Aout[row]      = (bf16_t)(oa0[r] * ir);
    Aout[row + 32] = (bf16_t)(oa1[r] * ir);
  }
}

// ---------------- launch ----------------
extern "C" void kernel_launch(void* const* d_in, const int* in_sizes, int n_in,
                              void* d_out, int out_size, void* d_ws, size_t ws_size,
                              hipStream_t stream) {
  const float* x    = (const float*)d_in[0];
  const float* Wqkv = (const float*)d_in[1];
  const float* bqkv = (const float*)d_in[2];
  const float* Wout = (const float*)d_in[3];
  const float* bout = (const float*)d_in[4];
  float* out = (float*)d_out;

  char* ws = (char*)d_ws;
  bf16_t* xb    = (bf16_t*)(ws);                 // 16 MB
  bf16_t* wqkvb = (bf16_t*)(ws + 16777216);      // 6 MB
  bf16_t* woutb = (bf16_t*)(ws + 23068672);      // 2 MB
  bf16_t* Qw    = (bf16_t*)(ws + 25165824);      // 16 MB (pre-scaled by log2e/8)
  bf16_t* Kw    = (bf16_t*)(ws + 41943040);      // 16 MB
  bf16_t* VT    = (bf16_t*)(ws + 58720256);      // 16 MB (transposed V)
  bf16_t* aout  = (bf16_t*)(ws + 75497472);      // 16 MB

  cvt_f32_bf16<<<8192, 256, 0, stream>>>(x, xb, 2097152);
  cvt_f32_bf16<<<3072, 256, 0, stream>>>(Wqkv, wqkvb, 786432);
  cvt_f32_bf16<<<1024, 256, 0, stream>>>(Wout, woutb, 262144);

  gemm_qkv<<<dim3(24, 64), 256, 0, stream>>>(xb, wqkvb, bqkv, Qw, Kw, VT);
  attn_fwd<<<1024, 256, 0, stream>>>(Qw, Kw, VT, aout);
  gemm_out<<<dim3(8, 64), 256, 0, stream>>>(aout, woutb, bout, out);
}

// Round 3
// 359.097 us; speedup vs baseline: 1.6059x; 1.0048x over previous
//
#include <hip/hip_runtime.h>
#include <hip/hip_bf16.h>
#include <cstdint>
#include <cstddef>

typedef __bf16 bf16_t;
typedef bf16_t bf16x8 __attribute__((ext_vector_type(8)));
typedef bf16_t bf16x4 __attribute__((ext_vector_type(4)));
typedef bf16_t bf16x2 __attribute__((ext_vector_type(2)));
typedef float f32x4 __attribute__((ext_vector_type(4)));
typedef float f32x16 __attribute__((ext_vector_type(16)));
typedef unsigned int u32x4 __attribute__((ext_vector_type(4)));

#define B_  4
#define S_  2048
#define D_  1024
#define H_  16
#define DK_ 64

// log2(e)/8 : folds the 1/sqrt(64) softmax scale AND ln->log2 conversion into Q.
#define QSCALE 0.18033688011112042f

// async global->LDS, 16B per lane. LDS dest must be wave-uniform base + lane*16.
__device__ __forceinline__ void gload_lds16(const bf16_t* g, bf16_t* l) {
  __builtin_amdgcn_global_load_lds(
      (__attribute__((address_space(1))) void*)(void*)g,
      (__attribute__((address_space(3))) void*)(void*)l,
      16, 0, 0);
}

__device__ __forceinline__ f32x4 mfma_bf16(bf16x8 a, bf16x8 b, f32x4 c) {
  return __builtin_amdgcn_mfma_f32_16x16x32_bf16(a, b, c, 0, 0, 0);
}
__device__ __forceinline__ f32x16 mfma32(bf16x8 a, bf16x8 b, f32x16 c) {
  return __builtin_amdgcn_mfma_f32_32x32x16_bf16(a, b, c, 0, 0, 0);
}

__device__ __forceinline__ unsigned pk2(float a, float b) {
  bf16x2 v; v[0] = (bf16_t)a; v[1] = (bf16_t)b;
  return __builtin_bit_cast(unsigned, v);
}

// ---------------- fp32 -> bf16 convert (vectorized) ----------------
__global__ void cvt_f32_bf16(const float* __restrict__ in, bf16_t* __restrict__ out, int n4) {
  int i = blockIdx.x * blockDim.x + threadIdx.x;
  if (i < n4) {
    float4 v = reinterpret_cast<const float4*>(in)[i];
    bf16x4 o;
    o[0] = (bf16_t)v.x; o[1] = (bf16_t)v.y; o[2] = (bf16_t)v.z; o[3] = (bf16_t)v.w;
    reinterpret_cast<bf16x4*>(out)[i] = o;
  }
}

// ---------------- GEMM 1: qkv = x @ Wqkv^T + bqkv, scatter to Q/K/V^T ----------------
__global__ __launch_bounds__(256) void gemm_qkv(
    const bf16_t* __restrict__ A, const bf16_t* __restrict__ Bm,
    const float* __restrict__ bias,
    bf16_t* __restrict__ Qw, bf16_t* __restrict__ Kw, bf16_t* __restrict__ VT) {
  __shared__ bf16_t As[128 * 32];
  __shared__ bf16_t Bs[128 * 32];
  const int t = threadIdx.x;
  const int l = t & 63;
  const int w = t >> 6;
  const int wm = w >> 1, wn = w & 1;
  const int fr = l & 15, fh = l >> 4;     // frag row / k-half
  const int m0 = blockIdx.y * 128, n0 = blockIdx.x * 128;
  const int K = 1024;
  const int ar = t >> 2, ak = (t & 3) * 8;

  f32x4 acc[4][4] = {};

  for (int k0 = 0; k0 < K; k0 += 32) {
    gload_lds16(A + (size_t)(m0 + ar) * K + k0 + ak,        &As[t * 8]);
    gload_lds16(A + (size_t)(m0 + 64 + ar) * K + k0 + ak,   &As[2048 + t * 8]);
    gload_lds16(Bm + (size_t)(n0 + ar) * K + k0 + ak,       &Bs[t * 8]);
    gload_lds16(Bm + (size_t)(n0 + 64 + ar) * K + k0 + ak,  &Bs[2048 + t * 8]);
    __syncthreads();
    bf16x8 af[4], bfv[4];
#pragma unroll
    for (int i = 0; i < 4; ++i)
      af[i] = *reinterpret_cast<const bf16x8*>(&As[(wm * 64 + i * 16 + fr) * 32 + fh * 8]);
#pragma unroll
    for (int i = 0; i < 4; ++i)
      bfv[i] = *reinterpret_cast<const bf16x8*>(&Bs[(wn * 64 + i * 16 + fr) * 32 + fh * 8]);
#pragma unroll
    for (int mi = 0; mi < 4; ++mi)
#pragma unroll
      for (int ni = 0; ni < 4; ++ni)
        acc[mi][ni] = mfma_bf16(af[mi], bfv[ni], acc[mi][ni]);
    __syncthreads();
  }

  // epilogue: C[m][e] + bias[e] -> scatter into Q (pre-scaled), K, V^T
#pragma unroll
  for (int mi = 0; mi < 4; ++mi) {
#pragma unroll
    for (int ni = 0; ni < 4; ++ni) {
      const int e = n0 + wn * 64 + ni * 16 + fr;
      const int sec = e >> 10;              // 0=q 1=k 2=v
      const int h = (e & 1023) >> 6, dk = e & 63;
      const float bv = bias[e];
#pragma unroll
      for (int j = 0; j < 4; ++j) {
        const int m = m0 + wm * 64 + mi * 16 + fh * 4 + j;
        const int b = m >> 11, s = m & 2047;
        const float val = acc[mi][ni][j] + bv;
        if (sec == 0)      Qw[((size_t)(b * H_ + h) * S_ + s) * DK_ + dk] = (bf16_t)(val * QSCALE);
        else if (sec == 1) Kw[((size_t)(b * H_ + h) * S_ + s) * DK_ + dk] = (bf16_t)val;
        else               VT[((size_t)(b * H_ + h) * DK_ + dk) * S_ + s] = (bf16_t)val;
      }
    }
  }
}

// ---------------- GEMM 2: out = attn_out @ Wout^T + bout (fp32 out) ----------------
__global__ __launch_bounds__(256) void gemm_out(
    const bf16_t* __restrict__ A, const bf16_t* __restrict__ Bm,
    const float* __restrict__ bias, float* __restrict__ out) {
  __shared__ bf16_t As[128 * 32];
  __shared__ bf16_t Bs[128 * 32];
  const int t = threadIdx.x;
  const int l = t & 63;
  const int w = t >> 6;
  const int wm = w >> 1, wn = w & 1;
  const int fr = l & 15, fh = l >> 4;
  const int m0 = blockIdx.y * 128, n0 = blockIdx.x * 128;
  const int K = 1024;
  const int ar = t >> 2, ak = (t & 3) * 8;

  f32x4 acc[4][4] = {};

  for (int k0 = 0; k0 < K; k0 += 32) {
    gload_lds16(A + (size_t)(m0 + ar) * K + k0 + ak,        &As[t * 8]);
    gload_lds16(A + (size_t)(m0 + 64 + ar) * K + k0 + ak,   &As[2048 + t * 8]);
    gload_lds16(Bm + (size_t)(n0 + ar) * K + k0 + ak,       &Bs[t * 8]);
    gload_lds16(Bm + (size_t)(n0 + 64 + ar) * K + k0 + ak,  &Bs[2048 + t * 8]);
    __syncthreads();
    bf16x8 af[4], bfv[4];
#pragma unroll
    for (int i = 0; i < 4; ++i)
      af[i] = *reinterpret_cast<const bf16x8*>(&As[(wm * 64 + i * 16 + fr) * 32 + fh * 8]);
#pragma unroll
    for (int i = 0; i < 4; ++i)
      bfv[i] = *reinterpret_cast<const bf16x8*>(&Bs[(wn * 64 + i * 16 + fr) * 32 + fh * 8]);
#pragma unroll
    for (int mi = 0; mi < 4; ++mi)
#pragma unroll
      for (int ni = 0; ni < 4; ++ni)
        acc[mi][ni] = mfma_bf16(af[mi], bfv[ni], acc[mi][ni]);
    __syncthreads();
  }

#pragma unroll
  for (int mi = 0; mi < 4; ++mi) {
#pragma unroll
    for (int ni = 0; ni < 4; ++ni) {
      const int e = n0 + wn * 64 + ni * 16 + fr;
      const float bv = bias[e];
#pragma unroll
      for (int j = 0; j < 4; ++j) {
        const int m = m0 + wm * 64 + mi * 16 + fh * 4 + j;
        out[(size_t)m * D_ + e] = acc[mi][ni][j] + bv;
      }
    }
  }
}

// ---------------- Flash attention, swapped-operand 32x32, split-kv x2 ----------------
// grid: 2048 blocks x 256 threads (4 waves). Block = 64 q-rows of one head.
// Wave w: q-sub (w&1)*32, kv-half (w>>1)*1024..+1024, processed as 32 tiles of kv32
// starting at a per-wave rotated offset (online softmax is order-invariant) to
// desync wave phases on a SIMD. Partner waves merged via LDS at the end.
__global__ __launch_bounds__(256) void attn_fwd(
    const bf16_t* __restrict__ Qw, const bf16_t* __restrict__ Kw,
    const bf16_t* __restrict__ VT, bf16_t* __restrict__ Aout) {
  __shared__ float lds_oa[2][32][64];
  __shared__ float lds_rs[2][64];
  __shared__ float lds_m[2];

  const int t = threadIdx.x, l = t & 63, w = t >> 6;
  const int lq = l & 31, hi = l >> 5;
  const int bid = (int)blockIdx.x;
  // bijective XCD swizzle: 2048 blocks, 8 XCDs -> 8 contiguous heads per XCD
  const int swz = (bid & 7) * 256 + (bid >> 3);
  const int bh = swz >> 5;                       // 0..63
  const int q0 = (swz & 31) * 64 + (w & 1) * 32; // wave's 32 q-rows
  const int kvh = w >> 1;
  const int b = bh >> 4, h = bh & 15;

  const bf16_t* Qh = Qw + (size_t)bh * S_ * DK_;
  const bf16_t* Kh = Kw + (size_t)bh * S_ * DK_;
  const bf16_t* Vh = VT + (size_t)bh * S_ * DK_;   // [DK][S]

  // Q B-operand frags: lane holds Q[q0+lq][d*16 + hi*8 .. +8]
  bf16x8 qf[4];
#pragma unroll
  for (int d = 0; d < 4; ++d)
    qf[d] = *reinterpret_cast<const bf16x8*>(&Qh[(size_t)(q0 + lq) * DK_ + d * 16 + hi * 8]);

  f32x16 oa0 = {}, oa1 = {};     // O accum: rows q=rowpat(r,hi), cols dk = lq (+32)
  float m = -1e30f, rs = 0.f;
  const int roto = w * 8;        // rotated kv-tile start per wave

  for (int it = 0; it < 32; ++it) {
    const int kv0 = kvh * 1024 + (((it + roto) & 31) << 5);

    // --- K loads (this tile) ---
    const bf16_t* kp = &Kh[(size_t)(kv0 + lq) * DK_ + hi * 8];
    bf16x8 k0 = *reinterpret_cast<const bf16x8*>(kp);
    bf16x8 k1 = *reinterpret_cast<const bf16x8*>(kp + 16);
    bf16x8 k2 = *reinterpret_cast<const bf16x8*>(kp + 32);
    bf16x8 k3 = *reinterpret_cast<const bf16x8*>(kp + 48);
    // --- V loads hoisted: latency hides under QK + softmax ---
    const bf16_t* vp0 = &Vh[(size_t)lq * S_ + kv0 + hi * 8];
    const bf16_t* vp1 = &Vh[(size_t)(32 + lq) * S_ + kv0 + hi * 8];
    bf16x8 v00 = *reinterpret_cast<const bf16x8*>(vp0);
    bf16x8 v10 = *reinterpret_cast<const bf16x8*>(vp0 + 16);
    bf16x8 v01 = *reinterpret_cast<const bf16x8*>(vp1);
    bf16x8 v11 = *reinterpret_cast<const bf16x8*>(vp1 + 16);

    // --- QK^T (swapped): cs = S^T[kv0+rowpat][q0+lq], log2 domain ---
    __builtin_amdgcn_s_setprio(1);
    f32x16 cs = {};
    cs = mfma32(k0, qf[0], cs);
    cs = mfma32(k1, qf[1], cs);
    cs = mfma32(k2, qf[2], cs);
    cs = mfma32(k3, qf[3], cs);
    __builtin_amdgcn_s_setprio(0);

    // --- tile max: pairwise tree (depth 4) ---
    float x0 = fmaxf(cs[0], cs[1]),  x1 = fmaxf(cs[2], cs[3]);
    float x2 = fmaxf(cs[4], cs[5]),  x3 = fmaxf(cs[6], cs[7]);
    float x4 = fmaxf(cs[8], cs[9]),  x5 = fmaxf(cs[10], cs[11]);
    float x6 = fmaxf(cs[12], cs[13]), x7 = fmaxf(cs[14], cs[15]);
    float y0 = fmaxf(x0, x1), y1 = fmaxf(x2, x3);
    float y2 = fmaxf(x4, x5), y3 = fmaxf(x6, x7);
    float tm = fmaxf(fmaxf(y0, y1), fmaxf(y2, y3));

    // --- deferred wave-uniform max update (T13, thr=8 in log2 domain) ---
    if (__any(tm > m + 8.f)) {
#pragma unroll
      for (int sh = 1; sh < 64; sh <<= 1) tm = fmaxf(tm, __shfl_xor(tm, sh));
      const float alpha = __builtin_amdgcn_exp2f(m - tm);
      m = tm;
      rs *= alpha;
#pragma unroll
      for (int r = 0; r < 16; ++r) { oa0[r] *= alpha; oa1[r] *= alpha; }
    }

    // --- exp2 (independent) + pairwise-tree sum ---
    float pv[16];
#pragma unroll
    for (int r = 0; r < 16; ++r) pv[r] = __builtin_amdgcn_exp2f(cs[r] - m);
    {
      float s0 = pv[0] + pv[1],   s1 = pv[2] + pv[3];
      float s2 = pv[4] + pv[5],   s3 = pv[6] + pv[7];
      float s4 = pv[8] + pv[9],   s5 = pv[10] + pv[11];
      float s6 = pv[12] + pv[13], s7 = pv[14] + pv[15];
      float u0 = s0 + s1, u1 = s2 + s3, u2 = s4 + s5, u3 = s6 + s7;
      rs += (u0 + u1) + (u2 + u3);
    }

    // --- pack pairs to bf16, exchange lane l <-> l+32, build A-frags ---
    unsigned Ab[4], Bb[4];
#pragma unroll
    for (int bb = 0; bb < 4; ++bb) {
      Ab[bb] = pk2(pv[4 * bb],     pv[4 * bb + 1]);
      Bb[bb] = pk2(pv[4 * bb + 2], pv[4 * bb + 3]);
    }
    bf16x8 pa[2];
#pragma unroll
    for (int tt = 0; tt < 2; ++tt) {
      const unsigned sA0 = (unsigned)__shfl_xor((int)Ab[2 * tt], 32);
      const unsigned sA1 = (unsigned)__shfl_xor((int)Ab[2 * tt + 1], 32);
      const unsigned sB0 = (unsigned)__shfl_xor((int)Bb[2 * tt], 32);
      const unsigned sB1 = (unsigned)__shfl_xor((int)Bb[2 * tt + 1], 32);
      u32x4 fw;
      fw[0] = hi ? sA1 : Ab[2 * tt];
      fw[1] = hi ? sB1 : Bb[2 * tt];
      fw[2] = hi ? Ab[2 * tt + 1] : sA0;
      fw[3] = hi ? Bb[2 * tt + 1] : sB0;
      pa[tt] = __builtin_bit_cast(bf16x8, fw);
    }
    // --- PV ---
    __builtin_amdgcn_s_setprio(1);
    oa0 = mfma32(pa[0], v00, oa0);
    oa1 = mfma32(pa[0], v01, oa1);
    oa0 = mfma32(pa[1], v10, oa0);
    oa1 = mfma32(pa[1], v11, oa1);
    __builtin_amdgcn_s_setprio(0);
  }

  rs += __shfl_xor(rs, 32);   // lane l and l+32 now both hold q=lq's sum

  // --- split-kv merge: waves 2,3 publish; waves 0,1 combine and write ---
  if (kvh == 1) {
    if (l == 0) lds_m[w & 1] = m;
    lds_rs[w & 1][l] = rs;
#pragma unroll
    for (int r = 0; r < 16; ++r) {
      lds_oa[w & 1][r][l]      = oa0[r];
      lds_oa[w & 1][16 + r][l] = oa1[r];
    }
  }
  __syncthreads();
  if (kvh == 0) {
    const int pr = w & 1;
    const float mB = lds_m[pr];
    const float mS = fmaxf(m, mB);
    const float aA = __builtin_amdgcn_exp2f(m - mS);
    const float aB = __builtin_amdgcn_exp2f(mB - mS);
    const float rsT = rs * aA + lds_rs[pr][l] * aB;
    const float inv = 1.0f / rsT;
#pragma unroll
    for (int r = 0; r < 16; ++r) {
      const int ql = (r & 3) + 8 * (r >> 2) + 4 * hi;
      const float ir = __shfl(inv, ql);
      const size_t row = (size_t)(b * S_ + q0 + ql) * D_ + h * 64 + lq;
      Aout[row]      = (bf16_t)((oa0[r] * aA + lds_oa[pr][r][l]      * aB) * ir);
      Aout[row + 32] = (bf16_t)((oa1[r] * aA + lds_oa[pr][16 + r][l] * aB) * ir);
    }
  }
}

// ---------------- launch ----------------
extern "C" void kernel_launch(void* const* d_in, const int* in_sizes, int n_in,
                              void* d_out, int out_size, void* d_ws, size_t ws_size,
                              hipStream_t stream) {
  const float* x    = (const float*)d_in[0];
  const float* Wqkv = (const float*)d_in[1];
  const float* bqkv = (const float*)d_in[2];
  const float* Wout = (const float*)d_in[3];
  const float* bout = (const float*)d_in[4];
  float* out = (float*)d_out;

  char* ws = (char*)d_ws;
  bf16_t* xb    = (bf16_t*)(ws);                 // 16 MB
  bf16_t* wqkvb = (bf16_t*)(ws + 16777216);      // 6 MB
  bf16_t* woutb = (bf16_t*)(ws + 23068672);      // 2 MB
  bf16_t* Qw    = (bf16_t*)(ws + 25165824);      // 16 MB (pre-scaled by log2e/8)
  bf16_t* Kw    = (bf16_t*)(ws + 41943040);      // 16 MB
  bf16_t* VT    = (bf16_t*)(ws + 58720256);      // 16 MB (transposed V)
  bf16_t* aout  = (bf16_t*)(ws + 75497472);      // 16 MB

  cvt_f32_bf16<<<8192, 256, 0, stream>>>(x, xb, 2097152);
  cvt_f32_bf16<<<3072, 256, 0, stream>>>(Wqkv, wqkvb, 786432);
  cvt_f32_bf16<<<1024, 256, 0, stream>>>(Wout, woutb, 262144);

  gemm_qkv<<<dim3(24, 64), 256, 0, stream>>>(xb, wqkvb, bqkv, Qw, Kw, VT);
  attn_fwd<<<2048, 256, 0, stream>>>(Qw, Kw, VT, aout);
  gemm_out<<<dim3(8, 64), 256, 0, stream>>>(aout, woutb, bout, out);
}

// Round 4
// 212.195 us; speedup vs baseline: 2.7177x; 1.6923x over previous
//
#include <hip/hip_runtime.h>
#include <hip/hip_bf16.h>
#include <cstdint>
#include <cstddef>

typedef __bf16 bf16_t;
typedef bf16_t bf16x8 __attribute__((ext_vector_type(8)));
typedef bf16_t bf16x4 __attribute__((ext_vector_type(4)));
typedef bf16_t bf16x2 __attribute__((ext_vector_type(2)));
typedef float f32x4 __attribute__((ext_vector_type(4)));
typedef float f32x16 __attribute__((ext_vector_type(16)));
typedef unsigned int u32x4 __attribute__((ext_vector_type(4)));

#define B_  4
#define S_  2048
#define D_  1024
#define H_  16
#define DK_ 64

// log2(e)/8 : folds the 1/sqrt(64) softmax scale AND ln->log2 conversion into Q.
#define QSCALE 0.18033688011112042f

// async global->LDS, 16B per lane. LDS dest must be wave-uniform base + lane*16.
__device__ __forceinline__ void gload_lds16(const bf16_t* g, bf16_t* l) {
  __builtin_amdgcn_global_load_lds(
      (__attribute__((address_space(1))) void*)(void*)g,
      (__attribute__((address_space(3))) void*)(void*)l,
      16, 0, 0);
}

__device__ __forceinline__ f32x4 mfma_bf16(bf16x8 a, bf16x8 b, f32x4 c) {
  return __builtin_amdgcn_mfma_f32_16x16x32_bf16(a, b, c, 0, 0, 0);
}
__device__ __forceinline__ f32x16 mfma32(bf16x8 a, bf16x8 b, f32x16 c) {
  return __builtin_amdgcn_mfma_f32_32x32x16_bf16(a, b, c, 0, 0, 0);
}

__device__ __forceinline__ unsigned pk2(float a, float b) {
  bf16x2 v; v[0] = (bf16_t)a; v[1] = (bf16_t)b;
  return __builtin_bit_cast(unsigned, v);
}

// ---------------- fp32 -> bf16 convert (vectorized) ----------------
__global__ void cvt_f32_bf16(const float* __restrict__ in, bf16_t* __restrict__ out, int n4) {
  int i = blockIdx.x * blockDim.x + threadIdx.x;
  if (i < n4) {
    float4 v = reinterpret_cast<const float4*>(in)[i];
    bf16x4 o;
    o[0] = (bf16_t)v.x; o[1] = (bf16_t)v.y; o[2] = (bf16_t)v.z; o[3] = (bf16_t)v.w;
    reinterpret_cast<bf16x4*>(out)[i] = o;
  }
}

// Fragment-order storage (per head, 131072 elements):
//  Q/K: element (s, dk) -> chunk t=s>>5, d=dk>>4; lane=(s&31)+((dk>>3)&1)*32; e=dk&7
//       idx = ((t*4+d)*64 + lane)*8 + e
//  V:   element (s, dk) -> t=s>>5, tt=(s>>4)&1, j=dk>>5; lane=(dk&31)+((s>>3)&1)*32; e=s&7
//       idx = (((t*2+tt)*2+j)*64 + lane)*8 + e
// attn then loads each MFMA fragment as one fully-coalesced 1KB global_load_dwordx4.

// ---------------- GEMM 1: qkv = x @ Wqkv^T + bqkv, scatter to Q/K/V frags ----------------
__global__ __launch_bounds__(256) void gemm_qkv(
    const bf16_t* __restrict__ A, const bf16_t* __restrict__ Bm,
    const float* __restrict__ bias,
    bf16_t* __restrict__ Qf, bf16_t* __restrict__ Kf, bf16_t* __restrict__ Vf) {
  __shared__ bf16_t As[128 * 32];
  __shared__ bf16_t Bs[128 * 32];
  const int t = threadIdx.x;
  const int l = t & 63;
  const int w = t >> 6;
  const int wm = w >> 1, wn = w & 1;
  const int fr = l & 15, fh = l >> 4;     // frag row / k-half
  const int m0 = blockIdx.y * 128, n0 = blockIdx.x * 128;
  const int K = 1024;
  const int ar = t >> 2, ak = (t & 3) * 8;

  f32x4 acc[4][4] = {};

  for (int k0 = 0; k0 < K; k0 += 32) {
    gload_lds16(A + (size_t)(m0 + ar) * K + k0 + ak,        &As[t * 8]);
    gload_lds16(A + (size_t)(m0 + 64 + ar) * K + k0 + ak,   &As[2048 + t * 8]);
    gload_lds16(Bm + (size_t)(n0 + ar) * K + k0 + ak,       &Bs[t * 8]);
    gload_lds16(Bm + (size_t)(n0 + 64 + ar) * K + k0 + ak,  &Bs[2048 + t * 8]);
    __syncthreads();
    bf16x8 af[4], bfv[4];
#pragma unroll
    for (int i = 0; i < 4; ++i)
      af[i] = *reinterpret_cast<const bf16x8*>(&As[(wm * 64 + i * 16 + fr) * 32 + fh * 8]);
#pragma unroll
    for (int i = 0; i < 4; ++i)
      bfv[i] = *reinterpret_cast<const bf16x8*>(&Bs[(wn * 64 + i * 16 + fr) * 32 + fh * 8]);
#pragma unroll
    for (int mi = 0; mi < 4; ++mi)
#pragma unroll
      for (int ni = 0; ni < 4; ++ni)
        acc[mi][ni] = mfma_bf16(af[mi], bfv[ni], acc[mi][ni]);
    __syncthreads();
  }

#pragma unroll
  for (int mi = 0; mi < 4; ++mi) {
#pragma unroll
    for (int ni = 0; ni < 4; ++ni) {
      const int e = n0 + wn * 64 + ni * 16 + fr;
      const int sec = e >> 10;              // 0=q 1=k 2=v
      const int h = (e & 1023) >> 6, dk = e & 63;
      const float bv = bias[e];
#pragma unroll
      for (int j = 0; j < 4; ++j) {
        const int m = m0 + wm * 64 + mi * 16 + fh * 4 + j;
        const int b = m >> 11, s = m & 2047;
        const float val = acc[mi][ni][j] + bv;
        const size_t hb = (size_t)(b * H_ + h) * (S_ * DK_);
        if (sec == 2) {
          const int tv = s >> 5, tt = (s >> 4) & 1, jj = dk >> 5;
          const int lane = (dk & 31) + ((s >> 3) & 1) * 32, el = s & 7;
          Vf[hb + (size_t)((((tv * 2 + tt) * 2 + jj) * 64 + lane) * 8 + el)] = (bf16_t)val;
        } else {
          const int tq = s >> 5, d = dk >> 4;
          const int lane = (s & 31) + ((dk >> 3) & 1) * 32, el = dk & 7;
          const size_t idx = hb + (size_t)(((tq * 4 + d) * 64 + lane) * 8 + el);
          if (sec == 0) Qf[idx] = (bf16_t)(val * QSCALE);
          else          Kf[idx] = (bf16_t)val;
        }
      }
    }
  }
}

// ---------------- GEMM 2: out = attn_out @ Wout^T + bout (fp32 out) ----------------
__global__ __launch_bounds__(256) void gemm_out(
    const bf16_t* __restrict__ A, const bf16_t* __restrict__ Bm,
    const float* __restrict__ bias, float* __restrict__ out) {
  __shared__ bf16_t As[128 * 32];
  __shared__ bf16_t Bs[128 * 32];
  const int t = threadIdx.x;
  const int l = t & 63;
  const int w = t >> 6;
  const int wm = w >> 1, wn = w & 1;
  const int fr = l & 15, fh = l >> 4;
  const int m0 = blockIdx.y * 128, n0 = blockIdx.x * 128;
  const int K = 1024;
  const int ar = t >> 2, ak = (t & 3) * 8;

  f32x4 acc[4][4] = {};

  for (int k0 = 0; k0 < K; k0 += 32) {
    gload_lds16(A + (size_t)(m0 + ar) * K + k0 + ak,        &As[t * 8]);
    gload_lds16(A + (size_t)(m0 + 64 + ar) * K + k0 + ak,   &As[2048 + t * 8]);
    gload_lds16(Bm + (size_t)(n0 + ar) * K + k0 + ak,       &Bs[t * 8]);
    gload_lds16(Bm + (size_t)(n0 + 64 + ar) * K + k0 + ak,  &Bs[2048 + t * 8]);
    __syncthreads();
    bf16x8 af[4], bfv[4];
#pragma unroll
    for (int i = 0; i < 4; ++i)
      af[i] = *reinterpret_cast<const bf16x8*>(&As[(wm * 64 + i * 16 + fr) * 32 + fh * 8]);
#pragma unroll
    for (int i = 0; i < 4; ++i)
      bfv[i] = *reinterpret_cast<const bf16x8*>(&Bs[(wn * 64 + i * 16 + fr) * 32 + fh * 8]);
#pragma unroll
    for (int mi = 0; mi < 4; ++mi)
#pragma unroll
      for (int ni = 0; ni < 4; ++ni)
        acc[mi][ni] = mfma_bf16(af[mi], bfv[ni], acc[mi][ni]);
    __syncthreads();
  }

#pragma unroll
  for (int mi = 0; mi < 4; ++mi) {
#pragma unroll
    for (int ni = 0; ni < 4; ++ni) {
      const int e = n0 + wn * 64 + ni * 16 + fr;
      const float bv = bias[e];
#pragma unroll
      for (int j = 0; j < 4; ++j) {
        const int m = m0 + wm * 64 + mi * 16 + fh * 4 + j;
        out[(size_t)m * D_ + e] = acc[mi][ni][j] + bv;
      }
    }
  }
}

// ---------------- Flash attention: frag-layout coalesced loads, K dbuf ----------------
// grid: 1024 blocks x 256 threads (4 waves). Block = 128 q of one head; wave = 32 q.
// All loads are coalesced 1KB chunks (frag-order storage). K double-buffered across
// a 2x-unrolled tile loop; V issued at phase top (covered by QK+softmax latency).
__global__ __launch_bounds__(256, 4) void attn_fwd(
    const bf16_t* __restrict__ Qf, const bf16_t* __restrict__ Kf,
    const bf16_t* __restrict__ Vf, bf16_t* __restrict__ Aout) {
  const int t = threadIdx.x, l = t & 63, w = t >> 6;
  const int lq = l & 31, hi = l >> 5;
  const int bid = (int)blockIdx.x;
  // bijective XCD swizzle: 1024 blocks -> 8 contiguous heads per XCD (K+V 4MB = L2)
  const int swz = (bid & 7) * 128 + (bid >> 3);
  const int bh = swz >> 4;                       // 0..63
  const int q0 = (swz & 15) * 128 + w * 32;      // wave's 32 q-rows
  const int b = bh >> 4, h = bh & 15;

  const bf16_t* Qh = Qf + (size_t)bh * (S_ * DK_);
  const bf16_t* Kh = Kf + (size_t)bh * (S_ * DK_) + (size_t)l * 8;
  const bf16_t* Vh = Vf + (size_t)bh * (S_ * DK_) + (size_t)l * 8;

  // Q frags (coalesced): lane l holds Q[q0+(l&31)][d*16+(l>>5)*8 ..+8]
  const int tq = q0 >> 5;
  bf16x8 qf[4];
#pragma unroll
  for (int d = 0; d < 4; ++d)
    qf[d] = *reinterpret_cast<const bf16x8*>(&Qh[(size_t)(((tq * 4 + d) * 64 + l) * 8)]);

  f32x16 oa0 = {}, oa1 = {};     // O accum: rows q=rowpat(r,hi), cols dk = lq (+32)
  float m = -1e30f, rs = 0.f;

  // preload K tile 0
  bf16x8 kA0, kA1, kA2, kA3, kB0, kB1, kB2, kB3;
  kA0 = *reinterpret_cast<const bf16x8*>(&Kh[0 * 512]);
  kA1 = *reinterpret_cast<const bf16x8*>(&Kh[1 * 512]);
  kA2 = *reinterpret_cast<const bf16x8*>(&Kh[2 * 512]);
  kA3 = *reinterpret_cast<const bf16x8*>(&Kh[3 * 512]);

#define ATTN_PHASE(KC0, KC1, KC2, KC3, KN0, KN1, KN2, KN3, CUR, NXT)                      \
  {                                                                                        \
    /* prefetch next tile's K */                                                           \
    KN0 = *reinterpret_cast<const bf16x8*>(&Kh[(size_t)(((NXT) * 4 + 0) * 512)]);          \
    KN1 = *reinterpret_cast<const bf16x8*>(&Kh[(size_t)(((NXT) * 4 + 1) * 512)]);          \
    KN2 = *reinterpret_cast<const bf16x8*>(&Kh[(size_t)(((NXT) * 4 + 2) * 512)]);          \
    KN3 = *reinterpret_cast<const bf16x8*>(&Kh[(size_t)(((NXT) * 4 + 3) * 512)]);          \
    /* current tile's V (used after softmax ~300cyc later) */                              \
    bf16x8 v00 = *reinterpret_cast<const bf16x8*>(&Vh[(size_t)((((CUR) * 2 + 0) * 2 + 0) * 512)]); \
    bf16x8 v01 = *reinterpret_cast<const bf16x8*>(&Vh[(size_t)((((CUR) * 2 + 0) * 2 + 1) * 512)]); \
    bf16x8 v10 = *reinterpret_cast<const bf16x8*>(&Vh[(size_t)((((CUR) * 2 + 1) * 2 + 0) * 512)]); \
    bf16x8 v11 = *reinterpret_cast<const bf16x8*>(&Vh[(size_t)((((CUR) * 2 + 1) * 2 + 1) * 512)]); \
    __builtin_amdgcn_s_setprio(1);                                                         \
    f32x16 cs = {};                                                                        \
    cs = mfma32(KC0, qf[0], cs);                                                           \
    cs = mfma32(KC1, qf[1], cs);                                                           \
    cs = mfma32(KC2, qf[2], cs);                                                           \
    cs = mfma32(KC3, qf[3], cs);                                                           \
    __builtin_amdgcn_s_setprio(0);                                                         \
    float x0 = fmaxf(cs[0], cs[1]),  x1 = fmaxf(cs[2], cs[3]);                             \
    float x2 = fmaxf(cs[4], cs[5]),  x3 = fmaxf(cs[6], cs[7]);                             \
    float x4 = fmaxf(cs[8], cs[9]),  x5 = fmaxf(cs[10], cs[11]);                           \
    float x6 = fmaxf(cs[12], cs[13]), x7 = fmaxf(cs[14], cs[15]);                          \
    float tm = fmaxf(fmaxf(fmaxf(x0, x1), fmaxf(x2, x3)),                                  \
                     fmaxf(fmaxf(x4, x5), fmaxf(x6, x7)));                                 \
    if (__any(tm > m + 8.f)) {                                                             \
      _Pragma("unroll")                                                                    \
      for (int sh = 1; sh < 64; sh <<= 1) tm = fmaxf(tm, __shfl_xor(tm, sh));              \
      const float alpha = __builtin_amdgcn_exp2f(m - tm);                                  \
      m = tm; rs *= alpha;                                                                 \
      _Pragma("unroll")                                                                    \
      for (int r = 0; r < 16; ++r) { oa0[r] *= alpha; oa1[r] *= alpha; }                   \
    }                                                                                      \
    float pv[16];                                                                          \
    _Pragma("unroll")                                                                      \
    for (int r = 0; r < 16; ++r) pv[r] = __builtin_amdgcn_exp2f(cs[r] - m);                \
    {                                                                                      \
      float s0 = pv[0] + pv[1],   s1 = pv[2] + pv[3];                                      \
      float s2 = pv[4] + pv[5],   s3 = pv[6] + pv[7];                                      \
      float s4 = pv[8] + pv[9],   s5 = pv[10] + pv[11];                                    \
      float s6 = pv[12] + pv[13], s7 = pv[14] + pv[15];                                    \
      rs += ((s0 + s1) + (s2 + s3)) + ((s4 + s5) + (s6 + s7));                             \
    }                                                                                      \
    _Pragma("unroll")                                                                      \
    for (int tt = 0; tt < 2; ++tt) {                                                       \
      const unsigned A0 = pk2(pv[8 * tt],     pv[8 * tt + 1]);                             \
      const unsigned B0 = pk2(pv[8 * tt + 2], pv[8 * tt + 3]);                             \
      const unsigned A1 = pk2(pv[8 * tt + 4], pv[8 * tt + 5]);                             \
      const unsigned B1 = pk2(pv[8 * tt + 6], pv[8 * tt + 7]);                             \
      const unsigned sA0 = (unsigned)__shfl_xor((int)A0, 32);                              \
      const unsigned sA1 = (unsigned)__shfl_xor((int)A1, 32);                              \
      const unsigned sB0 = (unsigned)__shfl_xor((int)B0, 32);                              \
      const unsigned sB1 = (unsigned)__shfl_xor((int)B1, 32);                              \
      u32x4 fw;                                                                            \
      fw[0] = hi ? sA1 : A0;                                                               \
      fw[1] = hi ? sB1 : B0;                                                               \
      fw[2] = hi ? A1 : sA0;                                                               \
      fw[3] = hi ? B1 : sB0;                                                               \
      const bf16x8 pa = __builtin_bit_cast(bf16x8, fw);                                    \
      __builtin_amdgcn_s_setprio(1);                                                       \
      oa0 = mfma32(pa, (tt ? v10 : v00), oa0);                                             \
      oa1 = mfma32(pa, (tt ? v11 : v01), oa1);                                             \
      __builtin_amdgcn_s_setprio(0);                                                       \
    }                                                                                      \
  }

  for (int it = 0; it < 64; it += 2) {
    ATTN_PHASE(kA0, kA1, kA2, kA3, kB0, kB1, kB2, kB3, it, it + 1)
    ATTN_PHASE(kB0, kB1, kB2, kB3, kA0, kA1, kA2, kA3, it + 1, (it + 2) & 63)
  }
#undef ATTN_PHASE

  // epilogue: combine lane-pair sums, redistribute 1/rs, write [B,S,D] bf16
  rs += __shfl_xor(rs, 32);
  const float inv = 1.0f / rs;
#pragma unroll
  for (int r = 0; r < 16; ++r) {
    const int ql = (r & 3) + 8 * (r >> 2) + 4 * hi;
    const float ir = __shfl(inv, ql);
    const size_t row = (size_t)(b * S_ + q0 + ql) * D_ + h * 64 + lq;
    Aout[row]      = (bf16_t)(oa0[r] * ir);
    Aout[row + 32] = (bf16_t)(oa1[r] * ir);
  }
}

// ---------------- launch ----------------
extern "C" void kernel_launch(void* const* d_in, const int* in_sizes, int n_in,
                              void* d_out, int out_size, void* d_ws, size_t ws_size,
                              hipStream_t stream) {
  const float* x    = (const float*)d_in[0];
  const float* Wqkv = (const float*)d_in[1];
  const float* bqkv = (const float*)d_in[2];
  const float* Wout = (const float*)d_in[3];
  const float* bout = (const float*)d_in[4];
  float* out = (float*)d_out;

  char* ws = (char*)d_ws;
  bf16_t* xb    = (bf16_t*)(ws);                 // 16 MB
  bf16_t* wqkvb = (bf16_t*)(ws + 16777216);      // 6 MB
  bf16_t* woutb = (bf16_t*)(ws + 23068672);      // 2 MB
  bf16_t* Qfr   = (bf16_t*)(ws + 25165824);      // 16 MB (frag-order, pre-scaled)
  bf16_t* Kfr   = (bf16_t*)(ws + 41943040);      // 16 MB (frag-order)
  bf16_t* Vfr   = (bf16_t*)(ws + 58720256);      // 16 MB (frag-order)
  bf16_t* aout  = (bf16_t*)(ws + 75497472);      // 16 MB

  cvt_f32_bf16<<<8192, 256, 0, stream>>>(x, xb, 2097152);
  cvt_f32_bf16<<<3072, 256, 0, stream>>>(Wqkv, wqkvb, 786432);
  cvt_f32_bf16<<<1024, 256, 0, stream>>>(Wout, woutb, 262144);

  gemm_qkv<<<dim3(24, 64), 256, 0, stream>>>(xb, wqkvb, bqkv, Qfr, Kfr, Vfr);
  attn_fwd<<<1024, 256, 0, stream>>>(Qfr, Kfr, Vfr, aout);
  gemm_out<<<dim3(8, 64), 256, 0, stream>>>(aout, woutb, bout, out);
}